// Round 16
// baseline (130.603 us; speedup 1.0000x reference)
//
#include <hip/hip_runtime.h>
#include <math.h>

typedef short short8 __attribute__((ext_vector_type(8)));
typedef float f32x4 __attribute__((ext_vector_type(4)));
typedef unsigned short US;

#if __has_builtin(__builtin_amdgcn_exp2f)
#define EXP2(x) __builtin_amdgcn_exp2f(x)
#else
#define EXP2(x) exp2f(x)
#endif
#define RCP(x) __builtin_amdgcn_rcpf(x)

#define C2 2.8853900817779268f  /* 2*log2(e) */

// ---------- helpers ----------
__device__ __forceinline__ float bf2f(US u) {
    return __uint_as_float(((unsigned int)u) << 16);
}
// exact RNE float->bf16
__device__ __forceinline__ US f2bf(float f) {
    unsigned int x = __float_as_uint(f);
    return (US)((x + 0x7FFFu + ((x >> 16) & 1u)) >> 16);
}
// round-half-up float->bf16 (cheap, <=0.5ulp)
__device__ __forceinline__ US f2bf_fast(float f) {
    return (US)((__float_as_uint(f) + 0x8000u) >> 16);
}

// B=4, N=M=256, D=256, H=128 (hard-coded)

// ---------- kernel 1: prep (casts + transposes) ----------
__global__ void prep_kernel(const float* __restrict__ x0, const float* __restrict__ x1,
                            const float* __restrict__ Wc1, const float* __restrict__ Wc2,
                            const float* __restrict__ Wm, const float* __restrict__ Wd1,
                            const float* __restrict__ Wd2, const float* __restrict__ Wb,
                            US* __restrict__ x0b, US* __restrict__ x1b,
                            US* __restrict__ x0lo, US* __restrict__ x1lo,
                            US* __restrict__ WcT1, US* __restrict__ WcT2,
                            US* __restrict__ WmT, US* __restrict__ WdT1, US* __restrict__ WdT2,
                            US* __restrict__ WbThi, US* __restrict__ WbTlo,
                            US* __restrict__ x0T, US* __restrict__ x1T) {
    const int id = blockIdx.x;
    const int t = threadIdx.x;
    if (id < 512) {
        const int tensor = id >> 8;
        const float* src = tensor ? x1 : x0;
        US* dhi = tensor ? x1b : x0b;
        US* dlo = tensor ? x1lo : x0lo;
        const int idx = (id & 255) * 256 + t;  // float4 index
        float4 v = ((const float4*)src)[idx];
        float f[4] = {v.x, v.y, v.z, v.w};
        ushort4 hi, lo;
        US* hp = (US*)&hi;
        US* lp = (US*)&lo;
        #pragma unroll
        for (int j = 0; j < 4; ++j) {
            US h = f2bf(f[j]);
            hp[j] = h;
            lp[j] = f2bf(f[j] - bf2f(h));
        }
        ((ushort4*)dhi)[idx] = hi;
        ((ushort4*)dlo)[idx] = lo;
    } else if (id < 1152) {
        const int j = id - 512;
        const int mat = j >> 7;
        const float* src = (mat == 0) ? Wc1 : (mat == 1) ? Wc2 : (mat == 2) ? Wm : (mat == 3) ? Wd1 : Wd2;
        US* dst = (mat == 0) ? WcT1 : (mat == 1) ? WcT2 : (mat == 2) ? WmT : (mat == 3) ? WdT1 : WdT2;
        const int el = (j & 127) * 256 + t;
        const int d = el >> 7, h = el & 127;
        dst[h * 256 + d] = f2bf(src[d * 128 + h]);
    } else if (id < 1408) {
        const int j = id - 1152;
        const int el = j * 256 + t;
        const int d = el >> 8, dp = el & 255;
        float v = Wb[d * 256 + dp];
        US h = f2bf(v);
        WbThi[dp * 256 + d] = h;
        WbTlo[dp * 256 + d] = f2bf(v - bf2f(h));
    } else {
        // x0/x1 transposes -> xT[b][d][n] bf16
        const int j = id - 1408;          // 0..1023
        const int tensor = j >> 9;
        const int j2 = j & 511;
        const int b = j2 >> 7;
        const int dp = j2 & 127;          // d-pair
        const float* src = tensor ? x1 : x0;
        US* dst = tensor ? x1T : x0T;
        float2 v = *(const float2*)(src + (size_t)(b * 256 + t) * 256 + dp * 2);
        dst[(size_t)(b * 256 + dp * 2) * 256 + t] = f2bf(v.x);
        dst[(size_t)(b * 256 + dp * 2 + 1) * 256 + t] = f2bf(v.y);
    }
}

// ---------- kernel 2: combo (512 threads) — blocks 0..191: small GEMMs (waves 0-3); 192..2239: dot scores ----------
__global__ __launch_bounds__(512, 4)
void combo_kernel(const US* __restrict__ x0b, const US* __restrict__ x0lo,
                  const US* __restrict__ x1b,
                  const US* __restrict__ WcT1, const US* __restrict__ WcT2,
                  const US* __restrict__ WmT,
                  const US* __restrict__ WbThi, const US* __restrict__ WbTlo,
                  const US* __restrict__ WdT1, const US* __restrict__ WdT2,
                  const float* __restrict__ x0, const float* __restrict__ x1,
                  const float* __restrict__ vd1, const float* __restrict__ vd2,
                  US* __restrict__ S1T, US* __restrict__ SXT,
                  float* __restrict__ S2, float* __restrict__ SY,
                  US* __restrict__ XBhi, US* __restrict__ XBlo,
                  float* __restrict__ sjt_s, float* __restrict__ sjt_d) {
    __shared__ __align__(16) US Wp[64 * 256];  // 32 KB h-half of W' (pre-scaled by C2), 4-bit XOR swizzle
    const int bid = blockIdx.x;
    const int t = threadIdx.x;
    const int lane = t & 63;
    const int w = t >> 6;          // 0..7
    const int arow = lane & 15;
    const int kgrp = lane >> 4;

    if (bid < 192) {
        // ================= small-GEMM branch (waves 0-3 only) =================
        if (w >= 4) return;
        const int id = bid;                   // 192 = 4b x 3which x 16rg
        const int rg = id & 15;
        const int t2 = id >> 4;               // 0..11
        const int b = t2 / 3;
        const int which = t2 - b * 3;

        const US* A = (which == 2 ? x1b : x0b) + (size_t)(b * 256 + rg * 16 + arow) * 256 + kgrp * 8;
        const US* Alo = x0lo + (size_t)(b * 256 + rg * 16 + arow) * 256 + kgrp * 8;

        const f32x4 vzero = {0.f, 0.f, 0.f, 0.f};
        f32x4 acc[4];
        #pragma unroll
        for (int cj = 0; cj < 4; ++cj) acc[cj] = vzero;

        if (which == 1) {
            #pragma unroll
            for (int kk = 0; kk < 8; ++kk) {
                short8 ahi = *(const short8*)(A + kk * 32);
                short8 alo = *(const short8*)(Alo + kk * 32);
                #pragma unroll
                for (int cj = 0; cj < 4; ++cj) {
                    const int ct = w * 4 + cj;
                    short8 bhi = *(const short8*)(WbThi + (ct * 16 + arow) * 256 + kk * 32 + kgrp * 8);
                    short8 blo = *(const short8*)(WbTlo + (ct * 16 + arow) * 256 + kk * 32 + kgrp * 8);
                    acc[cj] = __builtin_amdgcn_mfma_f32_16x16x32_bf16(ahi, bhi, acc[cj], 0, 0, 0);
                    acc[cj] = __builtin_amdgcn_mfma_f32_16x16x32_bf16(ahi, blo, acc[cj], 0, 0, 0);
                    acc[cj] = __builtin_amdgcn_mfma_f32_16x16x32_bf16(alo, bhi, acc[cj], 0, 0, 0);
                }
            }
            #pragma unroll
            for (int cj = 0; cj < 4; ++cj) {
                const int ct = w * 4 + cj;
                #pragma unroll
                for (int r = 0; r < 4; ++r) {
                    const int n = rg * 16 + kgrp * 4 + r;
                    const int dp = ct * 16 + arow;
                    float val = acc[cj][r];
                    US h = f2bf(val);
                    US l = f2bf(val - bf2f(h));
                    XBhi[(size_t)(b * 256 + n) * 256 + dp] = h;
                    XBlo[(size_t)(b * 256 + n) * 256 + dp] = l;
                }
            }
        } else {
            const US* WA = (which == 0) ? WcT1 : WcT2;
            #pragma unroll
            for (int kk = 0; kk < 8; ++kk) {
                short8 a = *(const short8*)(A + kk * 32);
                #pragma unroll
                for (int cj = 0; cj < 4; ++cj) {
                    const int ct = w * 4 + cj;
                    const US* brow = (ct < 8) ? (WA + (ct * 16 + arow) * 256)
                                              : (WmT + ((ct - 8) * 16 + arow) * 256);
                    short8 bf = *(const short8*)(brow + kk * 32 + kgrp * 8);
                    acc[cj] = __builtin_amdgcn_mfma_f32_16x16x32_bf16(a, bf, acc[cj], 0, 0, 0);
                }
            }
            #pragma unroll
            for (int cj = 0; cj < 4; ++cj) {
                const int ct = w * 4 + cj;
                #pragma unroll
                for (int r = 0; r < 4; ++r) {
                    const int row = rg * 16 + kgrp * 4 + r;
                    const int h = (ct < 8) ? ct * 16 + arow : (ct - 8) * 16 + arow;
                    float val = acc[cj][r];
                    if (which == 0) {
                        // S1T/SXT layout: [b][n=row][h] bf16 (contiguous h for final_probs)
                        US* dst = (ct < 8) ? S1T : SXT;
                        dst[(size_t)(b * 256 + row) * 128 + h] = f2bf(val);
                    } else {
                        float* dst = (ct < 8) ? S2 : SY;
                        dst[(size_t)(b * 256 + row) * 128 + h] = val;
                    }
                }
            }
        }
        return;
    }

    // ================= dot-scores branch =================
    // 2048 blocks: (mech, b, m); 8 waves x 32 n; TWO h-half passes with in-block restage (32 KB LDS)
    const int id2 = bid - 192;
    const int m    = id2 & 255;
    const int b    = (id2 >> 8) & 3;
    const int mech = id2 >> 10;
    const US* xA = (mech == 0 ? x0b : x1b) + (size_t)b * 65536;
    const float* yrow = (mech == 0 ? x1 : x0) + (size_t)(b * 256 + m) * 256;
    const US* WT = (mech == 0 ? WdT1 : WdT2);
    const float* v = (mech == 0 ? vd1 : vd2);
    float* out = (mech == 0 ? sjt_s : sjt_d) + (size_t)(b * 256 + m) * 256;

    const int dslot = t & 31;   // 16B block along d
    const int hset = t >> 5;    // 0..15 -> 4 rows each per half

    float pacc[2][4];
    #pragma unroll
    for (int i = 0; i < 2; ++i)
        #pragma unroll
        for (int r = 0; r < 4; ++r) pacc[i][r] = 0.f;
    float vsum = 0.f;

    #pragma unroll
    for (int p = 0; p < 2; ++p) {
        if (p) __syncthreads();    // all readers of Wp done before restage
        // ---- stage h-half: Wp[hq][d] = C2*y[d]*WT[p*64+hq][d], slot ^= (hq&15) ----
        {
            float yv[8];
            float4 y0 = *(const float4*)(yrow + dslot * 8);
            float4 y1 = *(const float4*)(yrow + dslot * 8 + 4);
            yv[0] = y0.x * C2; yv[1] = y0.y * C2; yv[2] = y0.z * C2; yv[3] = y0.w * C2;
            yv[4] = y1.x * C2; yv[5] = y1.y * C2; yv[6] = y1.z * C2; yv[7] = y1.w * C2;
            #pragma unroll
            for (int k = 0; k < 4; ++k) {
                const int hq = hset * 4 + k;
                short8 wv = *(const short8*)(WT + (size_t)(p * 64 + hq) * 256 + dslot * 8);
                short8 ov;
                #pragma unroll
                for (int j = 0; j < 8; ++j)
                    ov[j] = (short)f2bf_fast(bf2f((US)wv[j]) * yv[j]);
                *(short8*)(&Wp[hq * 256 + ((dslot ^ (hq & 15)) << 3)]) = ov;
            }
        }
        __syncthreads();

        const f32x4 vzero = {0.f, 0.f, 0.f, 0.f};
        f32x4 acc[2][4];
        #pragma unroll
        for (int i = 0; i < 2; ++i)
            #pragma unroll
            for (int j = 0; j < 4; ++j) acc[i][j] = vzero;

        __builtin_amdgcn_s_setprio(1);
        #pragma unroll
        for (int kk = 0; kk < 8; ++kk) {
            short8 af[2];
            #pragma unroll
            for (int i = 0; i < 2; ++i)
                af[i] = *(const short8*)(xA + (size_t)(w * 32 + i * 16 + arow) * 256 + kk * 32 + kgrp * 8);
            const int sl = ((kk * 4 + kgrp) ^ arow) << 3;
            #pragma unroll
            for (int j = 0; j < 4; ++j) {
                short8 bfr = *(const short8*)(&Wp[(j * 16 + arow) * 256 + sl]);
                #pragma unroll
                for (int i = 0; i < 2; ++i)
                    acc[i][j] = __builtin_amdgcn_mfma_f32_16x16x32_bf16(af[i], bfr, acc[i][j], 0, 0, 0);
            }
        }
        __builtin_amdgcn_s_setprio(0);

        // fold: v*tanh(s) = v + (-2v)*rcp(exp2(C2*s)+1)  [C2*s already in acc]
        #pragma unroll
        for (int j = 0; j < 4; ++j) {
            const float vv = v[p * 64 + j * 16 + arow];
            vsum += vv;
            const float v2 = -2.0f * vv;
            #pragma unroll
            for (int i = 0; i < 2; ++i)
                #pragma unroll
                for (int r = 0; r < 4; ++r)
                    pacc[i][r] = fmaf(v2, RCP(EXP2(acc[i][j][r]) + 1.0f), pacc[i][r]);
        }
    }

    // reduce over the 16 h-lanes and write f32
    #pragma unroll
    for (int i = 0; i < 2; ++i)
        #pragma unroll
        for (int r = 0; r < 4; ++r) {
            float pp = pacc[i][r] + vsum;
            pp += __shfl_xor(pp, 1);
            pp += __shfl_xor(pp, 2);
            pp += __shfl_xor(pp, 4);
            pp += __shfl_xor(pp, 8);
            if (arow == 0) out[w * 32 + i * 16 + kgrp * 4 + r] = pp;
        }
}

// ---------- kernel 3: bilinear scores (hi/lo split, 3-MFMA, f32 out; 256 blocks) ----------
__global__ __launch_bounds__(256)
void bilinear_kernel(const US* __restrict__ x1b, const US* __restrict__ x1lo,
                     const US* __restrict__ XBhi, const US* __restrict__ XBlo,
                     float* __restrict__ sjt_b) {
    const int id = blockIdx.x;  // 256 = 4b x 8mt x 8nq
    const int b = id >> 6;
    const int rem = id & 63;
    const int mt = rem >> 3;    // 32-row m tile
    const int nq = rem & 7;     // 32-col n tile
    const int t = threadIdx.x;
    const int lane = t & 63;
    const int w = t >> 6;
    const int arow = lane & 15;
    const int kgrp = lane >> 4;
    const int m0 = mt * 32 + (w & 1) * 16;
    const int nt = nq * 2 + (w >> 1);
    const size_t abase = (size_t)(b * 256 + m0 + arow) * 256 + kgrp * 8;
    const size_t bbase0 = (size_t)(b * 256 + nt * 16 + arow) * 256 + kgrp * 8;
    const f32x4 vzero = {0.f, 0.f, 0.f, 0.f};
    f32x4 acc = vzero;
    #pragma unroll
    for (int kk = 0; kk < 8; ++kk) {
        short8 ahi = *(const short8*)(x1b + abase + kk * 32);
        short8 alo = *(const short8*)(x1lo + abase + kk * 32);
        short8 bhi = *(const short8*)(XBhi + bbase0 + kk * 32);
        short8 blo = *(const short8*)(XBlo + bbase0 + kk * 32);
        acc = __builtin_amdgcn_mfma_f32_16x16x32_bf16(ahi, bhi, acc, 0, 0, 0);
        acc = __builtin_amdgcn_mfma_f32_16x16x32_bf16(ahi, blo, acc, 0, 0, 0);
        acc = __builtin_amdgcn_mfma_f32_16x16x32_bf16(alo, bhi, acc, 0, 0, 0);
    }
    float* outb = sjt_b + (size_t)b * 65536;
    #pragma unroll
    for (int r = 0; r < 4; ++r)
        outb[(size_t)(m0 + kgrp * 4 + r) * 256 + nt * 16 + arow] = acc[r];
}

// ---------- kernel 4: concat+minus scores + 5x softmax -> P (bf16 probs) ----------
__global__ void final_probs_kernel(const US* __restrict__ S1T, const US* __restrict__ SXT,
                                   const float* __restrict__ S2, const float* __restrict__ SY,
                                   const float* __restrict__ vc, const float* __restrict__ vm,
                                   const float* __restrict__ sjt_b,
                                   const float* __restrict__ sjt_s, const float* __restrict__ sjt_d,
                                   US* __restrict__ P) {
    __shared__ float srow[5][256];
    __shared__ float s2c[128], syc[128], vc2[128], vm2[128];
    __shared__ float vsums[2];
    const int id = blockIdx.x;
    const int b = id >> 8, m = id & 255;
    const int t = threadIdx.x;
    const size_t bm = (size_t)(b * 256 + m) * 256;

    if (t < 128) {
        s2c[t] = S2[(size_t)(b * 256 + m) * 128 + t] * C2;
        vc2[t] = -2.0f * vc[t];
    } else {
        const int h = t - 128;
        syc[h] = SY[(size_t)(b * 256 + m) * 128 + h] * C2;
        vm2[h] = -2.0f * vm[h];
    }
    if (t < 64) {
        float sv = vc[t] + vc[t + 64];
        #pragma unroll
        for (int off = 32; off >= 1; off >>= 1) sv += __shfl_xor(sv, off);
        if (t == 0) vsums[0] = sv;
    } else if (t < 128) {
        const int l = t - 64;
        float sv = vm[l] + vm[l + 64];
        #pragma unroll
        for (int off = 32; off >= 1; off >>= 1) sv += __shfl_xor(sv, off);
        if (l == 0) vsums[1] = sv;
    }
    __syncthreads();

    // concat + minus score for column n=t of row m (S1T/SXT are [b][n][h], h contiguous)
    {
        const US* s1p = S1T + (size_t)(b * 256 + t) * 128;
        const US* sxp = SXT + (size_t)(b * 256 + t) * 128;
        float accC = 0.f, accM = 0.f;
        #pragma unroll 2
        for (int hb = 0; hb < 16; ++hb) {
            short8 s1v = *(const short8*)(s1p + hb * 8);
            short8 sxv = *(const short8*)(sxp + hb * 8);
            #pragma unroll
            for (int j = 0; j < 8; ++j) {
                const int h = hb * 8 + j;
                float s1 = bf2f((US)s1v[j]);
                float sx = bf2f((US)sxv[j]);
                float aC = fmaf(s1, C2, s2c[h]);
                float aM = fmaf(sx, C2, -syc[h]);
                accC = fmaf(vc2[h], RCP(EXP2(aC) + 1.0f), accC);
                accM = fmaf(vm2[h], RCP(EXP2(aM) + 1.0f), accM);
            }
        }
        srow[0][t] = accC + vsums[0];
        srow[1][t] = accM + vsums[1];
    }
    srow[2][t] = sjt_b[bm + t];
    srow[3][t] = sjt_s[bm + t];
    srow[4][t] = sjt_d[bm + t];
    __syncthreads();

    const int wv = t >> 6, lane = t & 63;
    for (int r = wv; r < 5; r += 4) {
        float v0 = srow[r][lane], v1 = srow[r][lane + 64];
        float v2 = srow[r][lane + 128], v3 = srow[r][lane + 192];
        float mx = fmaxf(fmaxf(v0, v1), fmaxf(v2, v3));
        #pragma unroll
        for (int off = 32; off >= 1; off >>= 1) mx = fmaxf(mx, __shfl_xor(mx, off));
        v0 = __expf(v0 - mx); v1 = __expf(v1 - mx);
        v2 = __expf(v2 - mx); v3 = __expf(v3 - mx);
        float s = v0 + v1 + v2 + v3;
        #pragma unroll
        for (int off = 32; off >= 1; off >>= 1) s += __shfl_xor(s, off);
        float inv = __fdividef(1.0f, s);
        srow[r][lane] = v0 * inv;       srow[r][lane + 64] = v1 * inv;
        srow[r][lane + 128] = v2 * inv; srow[r][lane + 192] = v3 * inv;
    }
    __syncthreads();

    // write probs (bf16), P[r][b][m][n]
    #pragma unroll
    for (int r = 0; r < 5; ++r)
        P[(size_t)r * 262144 + bm + t] = f2bf(srow[r][t]);
}

// ---------- kernel 5: apply — 5x weighted sums via MFMA + max with x1 (256 blocks) ----------
__global__ __launch_bounds__(256)
void apply_kernel(const US* __restrict__ P, const US* __restrict__ x0T,
                  const US* __restrict__ x1T, const float* __restrict__ x1,
                  float* __restrict__ outp) {
    const int id = blockIdx.x;  // 256 = 4b x 16dt x 4mq
    const int b = id >> 6;
    const int rem = id & 63;
    const int dt = rem >> 2;
    const int mq = rem & 3;
    const int t = threadIdx.x;
    const int lane = t & 63;
    const int w = t >> 6;
    const int arow = lane & 15;
    const int kgrp = lane >> 4;
    const int m0 = mq * 64 + w * 16;   // wave's 16 m-rows

    float vmax[4];
    #pragma unroll
    for (int r = 0; r < 4; ++r)
        vmax[r] = x1[(size_t)(b * 256 + m0 + kgrp * 4 + r) * 256 + dt * 16 + arow];

    const f32x4 vzero = {0.f, 0.f, 0.f, 0.f};
    #pragma unroll
    for (int mech = 0; mech < 5; ++mech) {
        const US* Bsrc = (mech == 4 ? x1T : x0T) + (size_t)(b * 256 + dt * 16 + arow) * 256;
        const US* Pm = P + (size_t)mech * 262144 + (size_t)(b * 256 + m0 + arow) * 256;
        f32x4 acc = vzero;
        #pragma unroll
        for (int kk = 0; kk < 8; ++kk) {
            short8 bf = *(const short8*)(Bsrc + kk * 32 + kgrp * 8);
            short8 af = *(const short8*)(Pm + kk * 32 + kgrp * 8);
            acc = __builtin_amdgcn_mfma_f32_16x16x32_bf16(af, bf, acc, 0, 0, 0);
        }
        #pragma unroll
        for (int r = 0; r < 4; ++r)
            vmax[r] = fmaxf(vmax[r], acc[r]);
    }

    #pragma unroll
    for (int r = 0; r < 4; ++r)
        outp[(size_t)(b * 256 + m0 + kgrp * 4 + r) * 256 + dt * 16 + arow] = vmax[r];
}

// ---------- host ----------
extern "C" void kernel_launch(void* const* d_in, const int* in_sizes, int n_in,
                              void* d_out, int out_size, void* d_ws, size_t ws_size,
                              hipStream_t stream) {
    (void)in_sizes; (void)n_in; (void)out_size; (void)ws_size;
    const float* x0  = (const float*)d_in[0];
    const float* x1  = (const float*)d_in[1];
    const float* Wc1 = (const float*)d_in[2];
    const float* Wc2 = (const float*)d_in[3];
    const float* vc  = (const float*)d_in[4];
    const float* Wb  = (const float*)d_in[5];
    const float* Wd1 = (const float*)d_in[6];
    const float* vd1 = (const float*)d_in[7];
    const float* Wd2 = (const float*)d_in[8];
    const float* vd2 = (const float*)d_in[9];
    const float* Wm  = (const float*)d_in[10];
    const float* vm  = (const float*)d_in[11];

    char* ws = (char*)d_ws;
    US*    x0b    = (US*)(ws + 0);          // 524288
    US*    x1b    = (US*)(ws + 524288);
    US*    x0lo   = (US*)(ws + 1048576);
    US*    x1lo   = (US*)(ws + 1572864);
    US*    WcT1   = (US*)(ws + 2097152);    // 65536 each
    US*    WcT2   = (US*)(ws + 2162688);
    US*    WmT    = (US*)(ws + 2228224);
    US*    WdT1   = (US*)(ws + 2293760);
    US*    WdT2   = (US*)(ws + 2359296);
    US*    WbThi  = (US*)(ws + 2424832);    // 131072 each
    US*    WbTlo  = (US*)(ws + 2555904);
    US*    S1T    = (US*)(ws + 2686976);    // 262144 each (bf16, [b][n][h])
    US*    SXT    = (US*)(ws + 2949120);
    float* S2     = (float*)(ws + 3211264); // 524288 each
    float* SY     = (float*)(ws + 3735552);
    US*    XBhi   = (US*)(ws + 4259840);    // 524288 each
    US*    XBlo   = (US*)(ws + 4784128);
    US*    x0T    = (US*)(ws + 5308416);    // 524288
    US*    x1T    = (US*)(ws + 5832704);    // 524288
    float* sjt_b  = (float*)(ws + 6356992); // 1048576 each (f32)
    float* sjt_s  = (float*)(ws + 7405568);
    float* sjt_d  = (float*)(ws + 8454144);
    US*    P      = (US*)(ws + 9502720);    // 5 x 524288 = 2621440 -> end 12124160

    prep_kernel<<<2432, 256, 0, stream>>>(x0, x1, Wc1, Wc2, Wm, Wd1, Wd2, Wb,
                                          x0b, x1b, x0lo, x1lo,
                                          WcT1, WcT2, WmT, WdT1, WdT2, WbThi, WbTlo,
                                          x0T, x1T);
    combo_kernel<<<2240, 512, 0, stream>>>(x0b, x0lo, x1b, WcT1, WcT2, WmT, WbThi, WbTlo,
                                           WdT1, WdT2, x0, x1, vd1, vd2,
                                           S1T, SXT, S2, SY, XBhi, XBlo, sjt_s, sjt_d);
    bilinear_kernel<<<256, 256, 0, stream>>>(x1b, x1lo, XBhi, XBlo, sjt_b);
    final_probs_kernel<<<1024, 256, 0, stream>>>(S1T, SXT, S2, SY, vc, vm, sjt_b,
                                                 sjt_s, sjt_d, P);
    apply_kernel<<<256, 256, 0, stream>>>(P, x0T, x1T, x1, (float*)d_out);
}

// Round 17
// 96.683 us; speedup vs baseline: 1.3508x; 1.3508x over previous
//
#include <hip/hip_runtime.h>
#include <math.h>

typedef short short8 __attribute__((ext_vector_type(8)));
typedef float f32x4 __attribute__((ext_vector_type(4)));
typedef unsigned short US;

#if __has_builtin(__builtin_amdgcn_exp2f)
#define EXP2(x) __builtin_amdgcn_exp2f(x)
#else
#define EXP2(x) exp2f(x)
#endif
#define RCP(x) __builtin_amdgcn_rcpf(x)

#define C2 2.8853900817779268f  /* 2*log2(e) */

// ---------- helpers ----------
__device__ __forceinline__ float bf2f(US u) {
    return __uint_as_float(((unsigned int)u) << 16);
}
// exact RNE float->bf16
__device__ __forceinline__ US f2bf(float f) {
    unsigned int x = __float_as_uint(f);
    return (US)((x + 0x7FFFu + ((x >> 16) & 1u)) >> 16);
}
// round-half-up float->bf16 (cheap, <=0.5ulp)
__device__ __forceinline__ US f2bf_fast(float f) {
    return (US)((__float_as_uint(f) + 0x8000u) >> 16);
}

// B=4, N=M=256, D=256, H=128 (hard-coded)

// ---------- kernel 1: prep (casts + transposes) ----------
__global__ void prep_kernel(const float* __restrict__ x0, const float* __restrict__ x1,
                            const float* __restrict__ Wc1, const float* __restrict__ Wc2,
                            const float* __restrict__ Wm, const float* __restrict__ Wd1,
                            const float* __restrict__ Wd2, const float* __restrict__ Wb,
                            US* __restrict__ x0b, US* __restrict__ x1b,
                            US* __restrict__ x0lo, US* __restrict__ x1lo,
                            US* __restrict__ WcT1, US* __restrict__ WcT2,
                            US* __restrict__ WmT, US* __restrict__ WdT1, US* __restrict__ WdT2,
                            US* __restrict__ WbThi, US* __restrict__ WbTlo,
                            US* __restrict__ x0T, US* __restrict__ x1T) {
    const int id = blockIdx.x;
    const int t = threadIdx.x;
    if (id < 512) {
        const int tensor = id >> 8;
        const float* src = tensor ? x1 : x0;
        US* dhi = tensor ? x1b : x0b;
        US* dlo = tensor ? x1lo : x0lo;
        const int idx = (id & 255) * 256 + t;  // float4 index
        float4 v = ((const float4*)src)[idx];
        float f[4] = {v.x, v.y, v.z, v.w};
        ushort4 hi, lo;
        US* hp = (US*)&hi;
        US* lp = (US*)&lo;
        #pragma unroll
        for (int j = 0; j < 4; ++j) {
            US h = f2bf(f[j]);
            hp[j] = h;
            lp[j] = f2bf(f[j] - bf2f(h));
        }
        ((ushort4*)dhi)[idx] = hi;
        ((ushort4*)dlo)[idx] = lo;
    } else if (id < 1152) {
        const int j = id - 512;
        const int mat = j >> 7;
        const float* src = (mat == 0) ? Wc1 : (mat == 1) ? Wc2 : (mat == 2) ? Wm : (mat == 3) ? Wd1 : Wd2;
        US* dst = (mat == 0) ? WcT1 : (mat == 1) ? WcT2 : (mat == 2) ? WmT : (mat == 3) ? WdT1 : WdT2;
        const int el = (j & 127) * 256 + t;
        const int d = el >> 7, h = el & 127;
        dst[h * 256 + d] = f2bf(src[d * 128 + h]);
    } else if (id < 1408) {
        const int j = id - 1152;
        const int el = j * 256 + t;
        const int d = el >> 8, dp = el & 255;
        float v = Wb[d * 256 + dp];
        US h = f2bf(v);
        WbThi[dp * 256 + d] = h;
        WbTlo[dp * 256 + d] = f2bf(v - bf2f(h));
    } else {
        // x0/x1 transposes -> xT[b][d][n] bf16
        const int j = id - 1408;          // 0..1023
        const int tensor = j >> 9;
        const int j2 = j & 511;
        const int b = j2 >> 7;
        const int dp = j2 & 127;          // d-pair
        const float* src = tensor ? x1 : x0;
        US* dst = tensor ? x1T : x0T;
        float2 v = *(const float2*)(src + (size_t)(b * 256 + t) * 256 + dp * 2);
        dst[(size_t)(b * 256 + dp * 2) * 256 + t] = f2bf(v.x);
        dst[(size_t)(b * 256 + dp * 2 + 1) * 256 + t] = f2bf(v.y);
    }
}

// ---------- kernel 2: combo (512 threads) — blocks 0..191: small GEMMs (waves 0-3); 192..2239: dot scores ----------
__global__ __launch_bounds__(512, 4)
void combo_kernel(const US* __restrict__ x0b, const US* __restrict__ x0lo,
                  const US* __restrict__ x1b,
                  const US* __restrict__ WcT1, const US* __restrict__ WcT2,
                  const US* __restrict__ WmT,
                  const US* __restrict__ WbThi, const US* __restrict__ WbTlo,
                  const US* __restrict__ WdT1, const US* __restrict__ WdT2,
                  const float* __restrict__ x0, const float* __restrict__ x1,
                  const float* __restrict__ vd1, const float* __restrict__ vd2,
                  US* __restrict__ S1T, US* __restrict__ SXT,
                  float* __restrict__ S2, float* __restrict__ SY,
                  US* __restrict__ XBhi, US* __restrict__ XBlo,
                  float* __restrict__ sjt_s, float* __restrict__ sjt_d) {
    __shared__ __align__(16) US Wp[128 * 256];  // 64 KB full W' (pre-scaled by C2), 4-bit XOR slot swizzle
    const int bid = blockIdx.x;
    const int t = threadIdx.x;
    const int lane = t & 63;
    const int w = t >> 6;          // 0..7
    const int arow = lane & 15;
    const int kgrp = lane >> 4;

    if (bid < 192) {
        // ================= small-GEMM branch (waves 0-3 only) =================
        if (w >= 4) return;
        const int id = bid;                   // 192 = 4b x 3which x 16rg
        const int rg = id & 15;
        const int t2 = id >> 4;               // 0..11
        const int b = t2 / 3;
        const int which = t2 - b * 3;

        const US* A = (which == 2 ? x1b : x0b) + (size_t)(b * 256 + rg * 16 + arow) * 256 + kgrp * 8;
        const US* Alo = x0lo + (size_t)(b * 256 + rg * 16 + arow) * 256 + kgrp * 8;

        const f32x4 vzero = {0.f, 0.f, 0.f, 0.f};
        f32x4 acc[4];
        #pragma unroll
        for (int cj = 0; cj < 4; ++cj) acc[cj] = vzero;

        if (which == 1) {
            #pragma unroll
            for (int kk = 0; kk < 8; ++kk) {
                short8 ahi = *(const short8*)(A + kk * 32);
                short8 alo = *(const short8*)(Alo + kk * 32);
                #pragma unroll
                for (int cj = 0; cj < 4; ++cj) {
                    const int ct = w * 4 + cj;
                    short8 bhi = *(const short8*)(WbThi + (ct * 16 + arow) * 256 + kk * 32 + kgrp * 8);
                    short8 blo = *(const short8*)(WbTlo + (ct * 16 + arow) * 256 + kk * 32 + kgrp * 8);
                    acc[cj] = __builtin_amdgcn_mfma_f32_16x16x32_bf16(ahi, bhi, acc[cj], 0, 0, 0);
                    acc[cj] = __builtin_amdgcn_mfma_f32_16x16x32_bf16(ahi, blo, acc[cj], 0, 0, 0);
                    acc[cj] = __builtin_amdgcn_mfma_f32_16x16x32_bf16(alo, bhi, acc[cj], 0, 0, 0);
                }
            }
            #pragma unroll
            for (int cj = 0; cj < 4; ++cj) {
                const int ct = w * 4 + cj;
                #pragma unroll
                for (int r = 0; r < 4; ++r) {
                    const int n = rg * 16 + kgrp * 4 + r;
                    const int dp = ct * 16 + arow;
                    float val = acc[cj][r];
                    US h = f2bf(val);
                    US l = f2bf(val - bf2f(h));
                    XBhi[(size_t)(b * 256 + n) * 256 + dp] = h;
                    XBlo[(size_t)(b * 256 + n) * 256 + dp] = l;
                }
            }
        } else {
            const US* WA = (which == 0) ? WcT1 : WcT2;
            #pragma unroll
            for (int kk = 0; kk < 8; ++kk) {
                short8 a = *(const short8*)(A + kk * 32);
                #pragma unroll
                for (int cj = 0; cj < 4; ++cj) {
                    const int ct = w * 4 + cj;
                    const US* brow = (ct < 8) ? (WA + (ct * 16 + arow) * 256)
                                              : (WmT + ((ct - 8) * 16 + arow) * 256);
                    short8 bf = *(const short8*)(brow + kk * 32 + kgrp * 8);
                    acc[cj] = __builtin_amdgcn_mfma_f32_16x16x32_bf16(a, bf, acc[cj], 0, 0, 0);
                }
            }
            #pragma unroll
            for (int cj = 0; cj < 4; ++cj) {
                const int ct = w * 4 + cj;
                #pragma unroll
                for (int r = 0; r < 4; ++r) {
                    const int row = rg * 16 + kgrp * 4 + r;
                    const int h = (ct < 8) ? ct * 16 + arow : (ct - 8) * 16 + arow;
                    float val = acc[cj][r];
                    if (which == 0) {
                        // S1T/SXT layout: [b][n=row][h] bf16 (contiguous h for final_probs)
                        US* dst = (ct < 8) ? S1T : SXT;
                        dst[(size_t)(b * 256 + row) * 128 + h] = f2bf(val);
                    } else {
                        float* dst = (ct < 8) ? S2 : SY;
                        dst[(size_t)(b * 256 + row) * 128 + h] = val;
                    }
                }
            }
        }
        return;
    }

    // ================= dot-scores branch =================
    // 2048 blocks: (mech, b, m); block = 8 waves x 32 n each x 128 h; stage ONCE, one barrier
    const int id2 = bid - 192;
    const int m    = id2 & 255;
    const int b    = (id2 >> 8) & 3;
    const int mech = id2 >> 10;
    const US* xA = (mech == 0 ? x0b : x1b) + (size_t)b * 65536;
    const float* yrow = (mech == 0 ? x1 : x0) + (size_t)(b * 256 + m) * 256;
    const US* WT = (mech == 0 ? WdT1 : WdT2);
    const float* v = (mech == 0 ? vd1 : vd2);
    float* out = (mech == 0 ? sjt_s : sjt_d) + (size_t)(b * 256 + m) * 256;

    // ---- stage full W'[hq][d] = C2*y[d]*WT[hq][d], slot ^= (hq&15); 512 threads x 8 rows ----
    {
        const int dslot = t & 31;   // 16B block along d
        const int hset = t >> 5;    // 0..15 -> 8 rows each
        float yv[8];
        float4 y0 = *(const float4*)(yrow + dslot * 8);
        float4 y1 = *(const float4*)(yrow + dslot * 8 + 4);
        yv[0] = y0.x * C2; yv[1] = y0.y * C2; yv[2] = y0.z * C2; yv[3] = y0.w * C2;
        yv[4] = y1.x * C2; yv[5] = y1.y * C2; yv[6] = y1.z * C2; yv[7] = y1.w * C2;
        #pragma unroll
        for (int k = 0; k < 8; ++k) {
            const int hq = hset * 8 + k;
            short8 wv = *(const short8*)(WT + (size_t)hq * 256 + dslot * 8);
            short8 ov;
            #pragma unroll
            for (int j = 0; j < 8; ++j)
                ov[j] = (short)f2bf_fast(bf2f((US)wv[j]) * yv[j]);
            *(short8*)(&Wp[hq * 256 + ((dslot ^ (hq & 15)) << 3)]) = ov;
        }
    }
    __syncthreads();

    float v2[8], vsum = 0.f;
    #pragma unroll
    for (int j = 0; j < 8; ++j) {
        const float vvv = v[j * 16 + arow];
        vsum += vvv;
        v2[j] = -2.0f * vvv;
    }

    const f32x4 vzero = {0.f, 0.f, 0.f, 0.f};
    f32x4 acc[2][8];
    #pragma unroll
    for (int i = 0; i < 2; ++i)
        #pragma unroll
        for (int j = 0; j < 8; ++j) acc[i][j] = vzero;

    __builtin_amdgcn_s_setprio(1);
    #pragma unroll
    for (int kk = 0; kk < 8; ++kk) {
        short8 af[2];
        #pragma unroll
        for (int i = 0; i < 2; ++i)
            af[i] = *(const short8*)(xA + (size_t)(w * 32 + i * 16 + arow) * 256 + kk * 32 + kgrp * 8);
        const int sl = ((kk * 4 + kgrp) ^ arow) << 3;
        #pragma unroll
        for (int j = 0; j < 8; ++j) {
            short8 bfr = *(const short8*)(&Wp[(j * 16 + arow) * 256 + sl]);
            #pragma unroll
            for (int i = 0; i < 2; ++i)
                acc[i][j] = __builtin_amdgcn_mfma_f32_16x16x32_bf16(af[i], bfr, acc[i][j], 0, 0, 0);
        }
    }
    __builtin_amdgcn_s_setprio(0);

    // fold: v*tanh(s) = v + v2*rcp(exp2(s*C2)+1)  [s*C2 already in acc]
    float pacc[2][4];
    #pragma unroll
    for (int i = 0; i < 2; ++i)
        #pragma unroll
        for (int r = 0; r < 4; ++r) pacc[i][r] = 0.f;
    #pragma unroll
    for (int j = 0; j < 8; ++j)
        #pragma unroll
        for (int i = 0; i < 2; ++i)
            #pragma unroll
            for (int r = 0; r < 4; ++r)
                pacc[i][r] = fmaf(v2[j], RCP(EXP2(acc[i][j][r]) + 1.0f), pacc[i][r]);

    // reduce over the 16 h-lanes and write f32
    #pragma unroll
    for (int i = 0; i < 2; ++i)
        #pragma unroll
        for (int r = 0; r < 4; ++r) {
            float pp = pacc[i][r] + vsum;
            pp += __shfl_xor(pp, 1);
            pp += __shfl_xor(pp, 2);
            pp += __shfl_xor(pp, 4);
            pp += __shfl_xor(pp, 8);
            if (arow == 0) out[w * 32 + i * 16 + kgrp * 4 + r] = pp;
        }
}

// ---------- kernel 3: bilinear scores (hi/lo split, 3-MFMA, f32 out; 256 blocks) ----------
__global__ __launch_bounds__(256)
void bilinear_kernel(const US* __restrict__ x1b, const US* __restrict__ x1lo,
                     const US* __restrict__ XBhi, const US* __restrict__ XBlo,
                     float* __restrict__ sjt_b) {
    const int id = blockIdx.x;  // 256 = 4b x 8mt x 8nq
    const int b = id >> 6;
    const int rem = id & 63;
    const int mt = rem >> 3;    // 32-row m tile
    const int nq = rem & 7;     // 32-col n tile
    const int t = threadIdx.x;
    const int lane = t & 63;
    const int w = t >> 6;
    const int arow = lane & 15;
    const int kgrp = lane >> 4;
    const int m0 = mt * 32 + (w & 1) * 16;
    const int nt = nq * 2 + (w >> 1);
    const size_t abase = (size_t)(b * 256 + m0 + arow) * 256 + kgrp * 8;
    const size_t bbase0 = (size_t)(b * 256 + nt * 16 + arow) * 256 + kgrp * 8;
    const f32x4 vzero = {0.f, 0.f, 0.f, 0.f};
    f32x4 acc = vzero;
    #pragma unroll
    for (int kk = 0; kk < 8; ++kk) {
        short8 ahi = *(const short8*)(x1b + abase + kk * 32);
        short8 alo = *(const short8*)(x1lo + abase + kk * 32);
        short8 bhi = *(const short8*)(XBhi + bbase0 + kk * 32);
        short8 blo = *(const short8*)(XBlo + bbase0 + kk * 32);
        acc = __builtin_amdgcn_mfma_f32_16x16x32_bf16(ahi, bhi, acc, 0, 0, 0);
        acc = __builtin_amdgcn_mfma_f32_16x16x32_bf16(ahi, blo, acc, 0, 0, 0);
        acc = __builtin_amdgcn_mfma_f32_16x16x32_bf16(alo, bhi, acc, 0, 0, 0);
    }
    float* outb = sjt_b + (size_t)b * 65536;
    #pragma unroll
    for (int r = 0; r < 4; ++r)
        outb[(size_t)(m0 + kgrp * 4 + r) * 256 + nt * 16 + arow] = acc[r];
}

// ---------- kernel 4: concat+minus scores + 5x softmax -> P (bf16 probs); 512 threads ----------
__global__ __launch_bounds__(512)
void final_probs_kernel(const US* __restrict__ S1T, const US* __restrict__ SXT,
                        const float* __restrict__ S2, const float* __restrict__ SY,
                        const float* __restrict__ vc, const float* __restrict__ vm,
                        const float* __restrict__ sjt_b,
                        const float* __restrict__ sjt_s, const float* __restrict__ sjt_d,
                        US* __restrict__ P) {
    __shared__ float srow[5][256];
    __shared__ float s2c[128], sycN[128], vc2l[128], vm2l[128];
    __shared__ float vsums[2];
    const int id = blockIdx.x;
    const int b = id >> 8, m = id & 255;
    const int t = threadIdx.x;
    const size_t bm = (size_t)(b * 256 + m) * 256;

    if (t < 128) {
        s2c[t] = S2[(size_t)(b * 256 + m) * 128 + t] * C2;
        vc2l[t] = -2.0f * vc[t];
    } else if (t < 256) {
        const int h = t - 128;
        sycN[h] = -SY[(size_t)(b * 256 + m) * 128 + h] * C2;
        vm2l[h] = -2.0f * vm[h];
    } else if (t < 320) {
        const int l = t - 256;
        float sv = vc[l] + vc[l + 64];
        #pragma unroll
        for (int off = 32; off >= 1; off >>= 1) sv += __shfl_xor(sv, off);
        if (l == 0) vsums[0] = sv;
    } else if (t < 384) {
        const int l = t - 320;
        float sv = vm[l] + vm[l + 64];
        #pragma unroll
        for (int off = 32; off >= 1; off >>= 1) sv += __shfl_xor(sv, off);
        if (l == 0) vsums[1] = sv;
    }
    // stage the three precomputed score rows
    {
        const int n = t & 255;
        if (t < 512) srow[2 + (t >> 8)][n] = (t < 256 ? sjt_b : sjt_s)[bm + n];
        if (t < 256) srow[4][t] = sjt_d[bm + t];
    }
    __syncthreads();

    // concat (threads 0-255) / minus (threads 256-511): column n, serial h-chain halved per thread
    {
        const int half = t >> 8;
        const int n = t & 255;
        const US* sp = (half == 0 ? S1T : SXT) + (size_t)(b * 256 + n) * 128;
        const float* scoef = half == 0 ? s2c : sycN;
        const float* vco = half == 0 ? vc2l : vm2l;
        float accv = 0.f;
        #pragma unroll 2
        for (int hb = 0; hb < 16; ++hb) {
            short8 v8 = *(const short8*)(sp + hb * 8);
            #pragma unroll
            for (int j = 0; j < 8; ++j) {
                const int h = hb * 8 + j;
                float a = fmaf(bf2f((US)v8[j]), C2, scoef[h]);
                accv = fmaf(vco[h], RCP(EXP2(a) + 1.0f), accv);
            }
        }
        srow[half][n] = accv + vsums[half];
    }
    __syncthreads();

    const int wv = t >> 6, lane = t & 63;
    for (int r = wv; r < 5; r += 8) {
        float v0 = srow[r][lane], v1 = srow[r][lane + 64];
        float v2 = srow[r][lane + 128], v3 = srow[r][lane + 192];
        float mx = fmaxf(fmaxf(v0, v1), fmaxf(v2, v3));
        #pragma unroll
        for (int off = 32; off >= 1; off >>= 1) mx = fmaxf(mx, __shfl_xor(mx, off));
        v0 = __expf(v0 - mx); v1 = __expf(v1 - mx);
        v2 = __expf(v2 - mx); v3 = __expf(v3 - mx);
        float s = v0 + v1 + v2 + v3;
        #pragma unroll
        for (int off = 32; off >= 1; off >>= 1) s += __shfl_xor(s, off);
        float inv = __fdividef(1.0f, s);
        srow[r][lane] = v0 * inv;       srow[r][lane + 64] = v1 * inv;
        srow[r][lane + 128] = v2 * inv; srow[r][lane + 192] = v3 * inv;
    }
    __syncthreads();

    // write probs (bf16), P[r][b][m][n]
    for (int idx = t; idx < 1280; idx += 512) {
        const int r = idx >> 8;
        const int n = idx & 255;
        P[(size_t)r * 262144 + bm + n] = f2bf(srow[r][n]);
    }
}

// ---------- kernel 5: apply — 5x weighted sums via MFMA + max with x1 (256 blocks) ----------
__global__ __launch_bounds__(256)
void apply_kernel(const US* __restrict__ P, const US* __restrict__ x0T,
                  const US* __restrict__ x1T, const float* __restrict__ x1,
                  float* __restrict__ outp) {
    const int id = blockIdx.x;  // 256 = 4b x 16dt x 4mq
    const int b = id >> 6;
    const int rem = id & 63;
    const int dt = rem >> 2;
    const int mq = rem & 3;
    const int t = threadIdx.x;
    const int lane = t & 63;
    const int w = t >> 6;
    const int arow = lane & 15;
    const int kgrp = lane >> 4;
    const int m0 = mq * 64 + w * 16;   // wave's 16 m-rows

    float vmax[4];
    #pragma unroll
    for (int r = 0; r < 4; ++r)
        vmax[r] = x1[(size_t)(b * 256 + m0 + kgrp * 4 + r) * 256 + dt * 16 + arow];

    const f32x4 vzero = {0.f, 0.f, 0.f, 0.f};
    #pragma unroll
    for (int mech = 0; mech < 5; ++mech) {
        const US* Bsrc = (mech == 4 ? x1T : x0T) + (size_t)(b * 256 + dt * 16 + arow) * 256;
        const US* Pm = P + (size_t)mech * 262144 + (size_t)(b * 256 + m0 + arow) * 256;
        f32x4 acc = vzero;
        #pragma unroll
        for (int kk = 0; kk < 8; ++kk) {
            short8 bf = *(const short8*)(Bsrc + kk * 32 + kgrp * 8);
            short8 af = *(const short8*)(Pm + kk * 32 + kgrp * 8);
            acc = __builtin_amdgcn_mfma_f32_16x16x32_bf16(af, bf, acc, 0, 0, 0);
        }
        #pragma unroll
        for (int r = 0; r < 4; ++r)
            vmax[r] = fmaxf(vmax[r], acc[r]);
    }

    #pragma unroll
    for (int r = 0; r < 4; ++r)
        outp[(size_t)(b * 256 + m0 + kgrp * 4 + r) * 256 + dt * 16 + arow] = vmax[r];
}

// ---------- host ----------
extern "C" void kernel_launch(void* const* d_in, const int* in_sizes, int n_in,
                              void* d_out, int out_size, void* d_ws, size_t ws_size,
                              hipStream_t stream) {
    (void)in_sizes; (void)n_in; (void)out_size; (void)ws_size;
    const float* x0  = (const float*)d_in[0];
    const float* x1  = (const float*)d_in[1];
    const float* Wc1 = (const float*)d_in[2];
    const float* Wc2 = (const float*)d_in[3];
    const float* vc  = (const float*)d_in[4];
    const float* Wb  = (const float*)d_in[5];
    const float* Wd1 = (const float*)d_in[6];
    const float* vd1 = (const float*)d_in[7];
    const float* Wd2 = (const float*)d_in[8];
    const float* vd2 = (const float*)d_in[9];
    const float* Wm  = (const float*)d_in[10];
    const float* vm  = (const float*)d_in[11];

    char* ws = (char*)d_ws;
    US*    x0b    = (US*)(ws + 0);          // 524288
    US*    x1b    = (US*)(ws + 524288);
    US*    x0lo   = (US*)(ws + 1048576);
    US*    x1lo   = (US*)(ws + 1572864);
    US*    WcT1   = (US*)(ws + 2097152);    // 65536 each
    US*    WcT2   = (US*)(ws + 2162688);
    US*    WmT    = (US*)(ws + 2228224);
    US*    WdT1   = (US*)(ws + 2293760);
    US*    WdT2   = (US*)(ws + 2359296);
    US*    WbThi  = (US*)(ws + 2424832);    // 131072 each
    US*    WbTlo  = (US*)(ws + 2555904);
    US*    S1T    = (US*)(ws + 2686976);    // 262144 each (bf16, [b][n][h])
    US*    SXT    = (US*)(ws + 2949120);
    float* S2     = (float*)(ws + 3211264); // 524288 each
    float* SY     = (float*)(ws + 3735552);
    US*    XBhi   = (US*)(ws + 4259840);    // 524288 each
    US*    XBlo   = (US*)(ws + 4784128);
    US*    x0T    = (US*)(ws + 5308416);    // 524288
    US*    x1T    = (US*)(ws + 5832704);    // 524288
    float* sjt_b  = (float*)(ws + 6356992); // 1048576 each (f32)
    float* sjt_s  = (float*)(ws + 7405568);
    float* sjt_d  = (float*)(ws + 8454144);
    US*    P      = (US*)(ws + 9502720);    // 5 x 524288 = 2621440 -> end 12124160

    prep_kernel<<<2432, 256, 0, stream>>>(x0, x1, Wc1, Wc2, Wm, Wd1, Wd2, Wb,
                                          x0b, x1b, x0lo, x1lo,
                                          WcT1, WcT2, WmT, WdT1, WdT2, WbThi, WbTlo,
                                          x0T, x1T);
    combo_kernel<<<2240, 512, 0, stream>>>(x0b, x0lo, x1b, WcT1, WcT2, WmT, WbThi, WbTlo,
                                           WdT1, WdT2, x0, x1, vd1, vd2,
                                           S1T, SXT, S2, SY, XBhi, XBlo, sjt_s, sjt_d);
    bilinear_kernel<<<256, 256, 0, stream>>>(x1b, x1lo, XBhi, XBlo, sjt_b);
    final_probs_kernel<<<1024, 512, 0, stream>>>(S1T, SXT, S2, SY, vc, vm, sjt_b,
                                                 sjt_s, sjt_d, P);
    apply_kernel<<<256, 256, 0, stream>>>(P, x0T, x1T, x1, (float*)d_out);
}